// Round 6
// baseline (309.421 us; speedup 1.0000x reference)
//
#include <hip/hip_runtime.h>
#include <math.h>

#define N 4096
#define DQ 128
#define DIN 64
#define DC 32
#define NT 9          // 9 n-tiles of 16: cols 0..127 = v, col 128 = p (z), 129..143 = 0
#define PSTRIDE 144
#define NIT (N / 16)  // 256 i-tiles

typedef __attribute__((ext_vector_type(8))) short short8;
typedef __attribute__((ext_vector_type(4))) float f32x4;

__device__ __forceinline__ unsigned short f2bf(float x) {
  unsigned u = __float_as_uint(x);
  return (unsigned short)((u + 0x7fffu + ((u >> 16) & 1u)) >> 16);
}
__device__ __forceinline__ float bf2f(unsigned short b) {
  return __uint_as_float(((unsigned)b) << 16);
}

// ---- shared epilogue: p*(h@W_av+b_av) -> bf16 hi/lo into LDS tile -----------
// LDS tile layout: sh[nt*128 + l15*8 + jj]  (nt = d>>4, l15 = d&15, jj = row r)
__device__ __forceinline__ void v_phase(const float* hs_row, float p,
    const float* __restrict__ W_av_k, const float* __restrict__ b_av_k,
    int r, int d4, unsigned short* shh, unsigned short* shl) {
  float a[4] = {b_av_k[d4], b_av_k[d4 + 1], b_av_k[d4 + 2], b_av_k[d4 + 3]};
  for (int c = 0; c < DQ; ++c) {
    const float hv = hs_row[c];
    const float4 w = *(const float4*)&W_av_k[c * DQ + d4];
    a[0] += hv * w.x; a[1] += hv * w.y; a[2] += hv * w.z; a[3] += hv * w.w;
  }
  const int nt = d4 >> 4;
#pragma unroll
  for (int e = 0; e < 4; ++e) {
    const float val = p * a[e];
    const unsigned short hi = f2bf(val);
    const unsigned short lo = f2bf(val - bf2f(hi));
    const int ix = nt * 128 + ((d4 + e) & 15) * 8 + r;
    shh[ix] = hi; shl[ix] = lo;
  }
  // z tile (nt=8): l15==0 -> p, l15 1..15 -> 0; threads c32<16 cover it
  const int c32 = d4 >> 2;
  if (c32 < 16) {
    const int ix = 8 * 128 + c32 * 8 + r;
    if (c32 == 0) {
      const unsigned short phi = f2bf(p);
      shh[ix] = phi; shl[ix] = f2bf(p - bf2f(phi));
    } else {
      shh[ix] = 0; shl[ix] = 0;
    }
  }
}

// coalesced store of the LDS tiles to the frag-ordered global arrays
__device__ __forceinline__ void v_store(int tid, int blk,
    const unsigned short* shh, const unsigned short* shl,
    unsigned short* __restrict__ Vhi, unsigned short* __restrict__ Vlo) {
  const int kt = blk >> 2, quad = blk & 3;
  if (tid < NT * 16) {
    const int nt = tid >> 4, l15 = tid & 15;
    const size_t dst = (((size_t)kt * NT + nt) * 64 + quad * 16 + l15) * 8;
    *(short8*)(Vhi + dst) = *(const short8*)&shh[nt * 128 + l15 * 8];
    *(short8*)(Vlo + dst) = *(const short8*)&shl[nt * 128 + l15 * 8];
  }
}

// ---- round 0: encode + sa + p + V' fused (8 rows per block) ----
__global__ __launch_bounds__(256) void kVS0(const float* __restrict__ x,
    const float* __restrict__ comms, const float* __restrict__ W_enc,
    const float* __restrict__ b_enc, const float* __restrict__ W_ad_k,
    const float* __restrict__ wa, const float* __restrict__ W_av_k,
    const float* __restrict__ b_av_k,
    unsigned short* __restrict__ Vhi, unsigned short* __restrict__ Vlo) {
  __shared__ float xs[8][96];
  __shared__ float hs[8][DQ];
  __shared__ float u[DQ];
  __shared__ float pb[8];
  __shared__ __align__(16) unsigned short shh[NT * 128];
  __shared__ __align__(16) unsigned short shl[NT * 128];
  const int tid = threadIdx.x;
  const int blk = blockIdx.x;
  if (tid < 128) {
    const float4 v = *(const float4*)&x[(size_t)blk * 8 * DIN + tid * 4];
    const int idx = tid * 4, r = idx >> 6, c = idx & 63;
    xs[r][c] = v.x; xs[r][c + 1] = v.y; xs[r][c + 2] = v.z; xs[r][c + 3] = v.w;
  } else if (tid < 192) {
    const int t = tid - 128;
    const float4 v = *(const float4*)&comms[(size_t)blk * 8 * DC + t * 4];
    const int idx = t * 4, r = idx >> 5, c = idx & 31;
    xs[r][64 + c] = v.x; xs[r][64 + c + 1] = v.y; xs[r][64 + c + 2] = v.z; xs[r][64 + c + 3] = v.w;
  }
  if (tid < DQ) {
    float s = 0.f;
    const float* wrow = &W_ad_k[tid * DQ];
    for (int q = 0; q < DQ; ++q) s += wrow[q] * wa[q];
    u[tid] = s;
  }
  __syncthreads();
  const int r = tid >> 5;
  const int c32 = tid & 31;
  const int d4 = c32 * 4;
  {
    float a0 = b_enc[d4], a1 = b_enc[d4 + 1], a2 = b_enc[d4 + 2], a3 = b_enc[d4 + 3];
    for (int c = 0; c < 96; ++c) {
      const float hv = xs[r][c];
      const float4 w = *(const float4*)&W_enc[c * DQ + d4];
      a0 += hv * w.x; a1 += hv * w.y; a2 += hv * w.z; a3 += hv * w.w;
    }
    hs[r][d4] = a0; hs[r][d4 + 1] = a1; hs[r][d4 + 2] = a2; hs[r][d4 + 3] = a3;
  }
  __syncthreads();
  float part = 0.f;
  for (int c = c32; c < DQ; c += 32) part += hs[r][c] * u[c];
#pragma unroll
  for (int m = 16; m > 0; m >>= 1) part += __shfl_xor(part, m, 32);
  if (c32 == 0) pb[r] = __expf(part);
  __syncthreads();
  v_phase(hs[r], pb[r], W_av_k, b_av_k, r, d4, shh, shl);
  __syncthreads();
  v_store(tid, blk, shh, shl, Vhi, Vlo);
}

// ---- rounds 1,2: P-reduce -> h + sa + p + V' fused (8 rows per block) ----
__global__ __launch_bounds__(256) void kVSR(const float* __restrict__ P,
    const float* __restrict__ W_ad_k, const float* __restrict__ wa,
    const float* __restrict__ W_av_k, const float* __restrict__ b_av_k,
    unsigned short* __restrict__ Vhi, unsigned short* __restrict__ Vlo,
    int ksplit) {
  __shared__ float hs[8][DQ];
  __shared__ float u[DQ];
  __shared__ float pb[8];
  __shared__ __align__(16) unsigned short shh[NT * 128];
  __shared__ __align__(16) unsigned short shl[NT * 128];
  const int tid = threadIdx.x;
  const int r = tid >> 5;
  const int c32 = tid & 31;
  const int d4 = c32 * 4;
  const int j = blockIdx.x * 8 + r;
  if (tid < DQ) {
    float s = 0.f;
    const float* wrow = &W_ad_k[tid * DQ];
    for (int q = 0; q < DQ; ++q) s += wrow[q] * wa[q];
    u[tid] = s;
  }
  float4 num = {0.f, 0.f, 0.f, 0.f};
  float den = 0.f;
  for (int s = 0; s < ksplit; ++s) {
    const float* b = &P[((size_t)s * N + j) * PSTRIDE];
    const float4 v = *(const float4*)&b[d4];
    num.x += v.x; num.y += v.y; num.z += v.z; num.w += v.w;
    den += b[128];
  }
  const float inv = 1.f / den;
  hs[r][d4] = num.x * inv; hs[r][d4 + 1] = num.y * inv;
  hs[r][d4 + 2] = num.z * inv; hs[r][d4 + 3] = num.w * inv;
  __syncthreads();
  float part = 0.f;
  for (int c = c32; c < DQ; c += 32) part += hs[r][c] * u[c];
#pragma unroll
  for (int m = 16; m > 0; m >>= 1) part += __shfl_xor(part, m, 32);
  if (c32 == 0) pb[r] = __expf(part);
  __syncthreads();
  v_phase(hs[r], pb[r], W_av_k, b_av_k, r, d4, shh, shl);
  __syncthreads();
  v_store(tid, blockIdx.x, shh, shl, Vhi, Vlo);
}

// ---- MFMA GEMM: P[s][i][d] = sum_j E[j][i] * V'[j,d], bf16 split-3 ----------
// One wave per block; each wave owns 2 i-tiles (32 rows) for register B reuse.
// PRE=false (round 0): A from strided trans + exp + split, store frags to Ehi/Elo.
// PRE=true (rounds 1,2): A = two coalesced short8 loads per tile from Ehi/Elo.
template <bool PRE>
__global__ __launch_bounds__(64) void kGemmM(const float* __restrict__ trans,
    unsigned short* __restrict__ Ehi, unsigned short* __restrict__ Elo,
    const unsigned short* __restrict__ Vhi, const unsigned short* __restrict__ Vlo,
    float* __restrict__ P, int kchunk) {
  const int lane = threadIdx.x;
  const int quad = lane >> 4, l15 = lane & 15;
  const int it0 = blockIdx.x * 2;                // two adjacent i-tiles
  const int i0 = it0 * 16;
  const int k0 = blockIdx.y * kchunk;
  const int nsteps = kchunk >> 5;

  f32x4 acc[2][NT];
#pragma unroll
  for (int ti = 0; ti < 2; ++ti)
#pragma unroll
    for (int nt = 0; nt < NT; ++nt) acc[ti][nt] = (f32x4){0.f, 0.f, 0.f, 0.f};

  float araw[2][8];
  short8 pah[2], pal[2];
  if (PRE) {
    const size_t kt = (size_t)(k0 >> 5);
#pragma unroll
    for (int ti = 0; ti < 2; ++ti) {
      const size_t ix = ((kt * NIT + it0 + ti) * 64 + lane) * 8;
      pah[ti] = *(const short8*)(Ehi + ix);
      pal[ti] = *(const short8*)(Elo + ix);
    }
  } else {
#pragma unroll
    for (int ti = 0; ti < 2; ++ti) {
      const float* aptr = trans + (size_t)(k0 + quad * 8) * N + i0 + ti * 16 + l15;
#pragma unroll
      for (int jj = 0; jj < 8; ++jj) araw[ti][jj] = aptr[(size_t)jj * N];
    }
  }

  for (int t = 0; t < nsteps; ++t) {
    const size_t kt = (size_t)(k0 >> 5) + t;
    short8 ah[2], al[2];
    if (PRE) {
      ah[0] = pah[0]; ah[1] = pah[1]; al[0] = pal[0]; al[1] = pal[1];
      if (t + 1 < nsteps) {
#pragma unroll
        for (int ti = 0; ti < 2; ++ti) {
          const size_t ix = (((kt + 1) * NIT + it0 + ti) * 64 + lane) * 8;
          pah[ti] = *(const short8*)(Ehi + ix);
          pal[ti] = *(const short8*)(Elo + ix);
        }
      }
    } else {
      float anext[2][8];
      if (t + 1 < nsteps) {
#pragma unroll
        for (int ti = 0; ti < 2; ++ti) {
          const float* ap2 = trans + (size_t)(k0 + (t + 1) * 32 + quad * 8) * N + i0 + ti * 16 + l15;
#pragma unroll
          for (int jj = 0; jj < 8; ++jj) anext[ti][jj] = ap2[(size_t)jj * N];
        }
      }
#pragma unroll
      for (int ti = 0; ti < 2; ++ti) {
        unsigned short hb[8], lb[8];
#pragma unroll
        for (int jj = 0; jj < 8; ++jj) {
          const float e = __expf(araw[ti][jj]);
          hb[jj] = f2bf(e);
          lb[jj] = f2bf(e - bf2f(hb[jj]));
        }
        ah[ti] = (short8){(short)hb[0], (short)hb[1], (short)hb[2], (short)hb[3],
                          (short)hb[4], (short)hb[5], (short)hb[6], (short)hb[7]};
        al[ti] = (short8){(short)lb[0], (short)lb[1], (short)lb[2], (short)lb[3],
                          (short)lb[4], (short)lb[5], (short)lb[6], (short)lb[7]};
        const size_t ix = ((kt * NIT + it0 + ti) * 64 + lane) * 8;
        *(short8*)(Ehi + ix) = ah[ti];
        *(short8*)(Elo + ix) = al[ti];
#pragma unroll
        for (int jj = 0; jj < 8; ++jj) araw[ti][jj] = anext[ti][jj];
      }
    }
    const unsigned short* bh = Vhi + (kt * NT * 64 + lane) * 8;
    const unsigned short* bl = Vlo + (kt * NT * 64 + lane) * 8;
#pragma unroll
    for (int nt = 0; nt < NT; ++nt) {
      const short8 bhv = *(const short8*)(bh + (size_t)nt * 512);
      const short8 blv = *(const short8*)(bl + (size_t)nt * 512);
#pragma unroll
      for (int ti = 0; ti < 2; ++ti) {
        acc[ti][nt] = __builtin_amdgcn_mfma_f32_16x16x32_bf16(ah[ti], bhv, acc[ti][nt], 0, 0, 0);
        acc[ti][nt] = __builtin_amdgcn_mfma_f32_16x16x32_bf16(ah[ti], blv, acc[ti][nt], 0, 0, 0);
        acc[ti][nt] = __builtin_amdgcn_mfma_f32_16x16x32_bf16(al[ti], bhv, acc[ti][nt], 0, 0, 0);
      }
    }
  }
  // C layout: col = lane&15, row = quad*4 + reg
  float* Pb = P + (size_t)blockIdx.y * N * PSTRIDE;
#pragma unroll
  for (int ti = 0; ti < 2; ++ti) {
#pragma unroll
    for (int nt = 0; nt < NT; ++nt) {
#pragma unroll
      for (int r = 0; r < 4; ++r) {
        const int i = i0 + ti * 16 + quad * 4 + r;
        Pb[(size_t)i * PSTRIDE + nt * 16 + l15] = acc[ti][nt][r];
      }
    }
  }
}

// ---- final: out[i] = (sum_d num[i][d] W_dec[d]) / den + b_dec ----
__global__ __launch_bounds__(256) void kOutR(const float* __restrict__ P,
    const float* __restrict__ W_dec, const float* __restrict__ b_dec,
    const int* __restrict__ mask, float* __restrict__ out, int ksplit) {
  __shared__ float red[256];
  const int tid = threadIdx.x;
  const int d = tid & 127;
  const int i = blockIdx.x * 2 + (tid >> 7);
  float num = 0.f, den = 0.f;
  for (int s = 0; s < ksplit; ++s) {
    const float* b = &P[((size_t)s * N + i) * PSTRIDE];
    num += b[d];
    den += b[128];
  }
  red[tid] = num * W_dec[d];
  __syncthreads();
  for (int st = 64; st > 0; st >>= 1) {
    if (d < st) red[tid] += red[tid + st];
    __syncthreads();
  }
  if (d == 0) out[i] = (mask[i] == 0) ? -INFINITY : red[tid] / den + b_dec[0];
}

extern "C" void kernel_launch(void* const* d_in, const int* in_sizes, int n_in,
                              void* d_out, int out_size, void* d_ws, size_t ws_size,
                              hipStream_t stream) {
  (void)in_sizes; (void)n_in; (void)out_size;
  const float* x     = (const float*)d_in[0];
  const float* comms = (const float*)d_in[1];
  const float* trans = (const float*)d_in[2];
  const int*   mask  = (const int*)d_in[3];
  const float* W_enc = (const float*)d_in[4];
  const float* b_enc = (const float*)d_in[5];
  const float* W_ad  = (const float*)d_in[6];
  // d_in[7]=b_ad, d_in[9]=b_att cancel inside the row softmax
  const float* w_att = (const float*)d_in[8];
  const float* W_av  = (const float*)d_in[10];
  const float* b_av  = (const float*)d_in[11];
  const float* W_dec = (const float*)d_in[12];
  const float* b_dec = (const float*)d_in[13];
  float* out         = (float*)d_out;

  char* ws = (char*)d_ws;
  unsigned short* Vhi = (unsigned short*)ws;  ws += (size_t)N * PSTRIDE * 2;
  unsigned short* Vlo = (unsigned short*)ws;  ws += (size_t)N * PSTRIDE * 2;
  unsigned short* Ehi = (unsigned short*)ws;  ws += (size_t)N * N * 2;
  unsigned short* Elo = (unsigned short*)ws;  ws += (size_t)N * N * 2;
  float* P = (float*)ws;
  const size_t fixedB = (size_t)N * PSTRIDE * 4 + (size_t)N * N * 4;
  const size_t perB   = (size_t)N * PSTRIDE * 4;          // one P split (fp32)
  const int ksplit = (ws_size >= fixedB + 32 * perB) ? 32
                   : (ws_size >= fixedB + 16 * perB) ? 16 : 8;
  const int kchunk = N / ksplit;

  for (int k = 0; k < 3; ++k) {
    const float* W_ad_k = W_ad + (size_t)k * DQ * DQ;
    const float* wa     = w_att + (size_t)k * 2 * DQ;
    const float* W_av_k = W_av + (size_t)k * DQ * DQ;
    const float* b_av_k = b_av + (size_t)k * DQ;
    if (k == 0) {
      kVS0<<<N / 8, 256, 0, stream>>>(x, comms, W_enc, b_enc, W_ad_k, wa,
                                      W_av_k, b_av_k, Vhi, Vlo);
      kGemmM<false><<<dim3(N / 32, ksplit), 64, 0, stream>>>(
          trans, Ehi, Elo, Vhi, Vlo, P, kchunk);
    } else {
      kVSR<<<N / 8, 256, 0, stream>>>(P, W_ad_k, wa, W_av_k, b_av_k,
                                      Vhi, Vlo, ksplit);
      kGemmM<true><<<dim3(N / 32, ksplit), 64, 0, stream>>>(
          trans, Ehi, Elo, Vhi, Vlo, P, kchunk);
    }
  }
  kOutR<<<N / 2, 256, 0, stream>>>(P, W_dec, b_dec, mask, out, ksplit);
}

// Round 7
// 257.843 us; speedup vs baseline: 1.2000x; 1.2000x over previous
//
#include <hip/hip_runtime.h>
#include <math.h>

#define N 4096
#define DQ 128
#define DIN 64
#define DC 32
#define NT 9          // 9 n-tiles of 16: cols 0..127 = v, col 128 = p (z), 129..143 = 0
#define PSTRIDE 144
#define NIT (N / 16)  // 256 i-tiles

typedef __attribute__((ext_vector_type(8))) short short8;
typedef __attribute__((ext_vector_type(8))) _Float16 half8;
typedef __attribute__((ext_vector_type(4))) float f32x4;

__device__ __forceinline__ unsigned short f2h(float x) {
  return __builtin_bit_cast(unsigned short, (_Float16)x);
}

// ---- shared epilogue: p*(h@W_av+b_av) -> f16 hi/lo into LDS tile -----------
// LDS tile layout: sh[nt*128 + l15*8 + jj]  (nt = d>>4, l15 = d&15, jj = row r)
__device__ __forceinline__ void v_phase(const float* hs_row, float p,
    const float* __restrict__ W_av_k, const float* __restrict__ b_av_k,
    int r, int d4, unsigned short* shh, unsigned short* shl) {
  float a[4] = {b_av_k[d4], b_av_k[d4 + 1], b_av_k[d4 + 2], b_av_k[d4 + 3]};
  for (int c = 0; c < DQ; ++c) {
    const float hv = hs_row[c];
    const float4 w = *(const float4*)&W_av_k[c * DQ + d4];
    a[0] += hv * w.x; a[1] += hv * w.y; a[2] += hv * w.z; a[3] += hv * w.w;
  }
  const int nt = d4 >> 4;
#pragma unroll
  for (int e = 0; e < 4; ++e) {
    const float val = p * a[e];
    const _Float16 hi = (_Float16)val;
    const _Float16 lo = (_Float16)(val - (float)hi);
    const int ix = nt * 128 + ((d4 + e) & 15) * 8 + r;
    shh[ix] = __builtin_bit_cast(unsigned short, hi);
    shl[ix] = __builtin_bit_cast(unsigned short, lo);
  }
  // z tile (nt=8): l15==0 -> p, l15 1..15 -> 0; threads c32<16 cover it
  const int c32 = d4 >> 2;
  if (c32 < 16) {
    const int ix = 8 * 128 + c32 * 8 + r;
    if (c32 == 0) {
      const _Float16 phi = (_Float16)p;
      const _Float16 plo = (_Float16)(p - (float)phi);
      shh[ix] = __builtin_bit_cast(unsigned short, phi);
      shl[ix] = __builtin_bit_cast(unsigned short, plo);
    } else {
      shh[ix] = 0; shl[ix] = 0;
    }
  }
}

// coalesced store of the LDS tiles to the frag-ordered global arrays
__device__ __forceinline__ void v_store(int tid, int blk,
    const unsigned short* shh, const unsigned short* shl,
    unsigned short* __restrict__ Vhi, unsigned short* __restrict__ Vlo) {
  const int kt = blk >> 2, quad = blk & 3;
  if (tid < NT * 16) {
    const int nt = tid >> 4, l15 = tid & 15;
    const size_t dst = (((size_t)kt * NT + nt) * 64 + quad * 16 + l15) * 8;
    *(short8*)(Vhi + dst) = *(const short8*)&shh[nt * 128 + l15 * 8];
    *(short8*)(Vlo + dst) = *(const short8*)&shl[nt * 128 + l15 * 8];
  }
}

// ---- round 0: encode + sa + p + V' fused (8 rows per block) ----
__global__ __launch_bounds__(256) void kVS0(const float* __restrict__ x,
    const float* __restrict__ comms, const float* __restrict__ W_enc,
    const float* __restrict__ b_enc, const float* __restrict__ W_ad_k,
    const float* __restrict__ wa, const float* __restrict__ W_av_k,
    const float* __restrict__ b_av_k,
    unsigned short* __restrict__ Vhi, unsigned short* __restrict__ Vlo) {
  __shared__ float xs[8][96];
  __shared__ float hs[8][DQ];
  __shared__ float u[DQ];
  __shared__ float pb[8];
  __shared__ __align__(16) unsigned short shh[NT * 128];
  __shared__ __align__(16) unsigned short shl[NT * 128];
  const int tid = threadIdx.x;
  const int blk = blockIdx.x;
  if (tid < 128) {
    const float4 v = *(const float4*)&x[(size_t)blk * 8 * DIN + tid * 4];
    const int idx = tid * 4, r = idx >> 6, c = idx & 63;
    xs[r][c] = v.x; xs[r][c + 1] = v.y; xs[r][c + 2] = v.z; xs[r][c + 3] = v.w;
  } else if (tid < 192) {
    const int t = tid - 128;
    const float4 v = *(const float4*)&comms[(size_t)blk * 8 * DC + t * 4];
    const int idx = t * 4, r = idx >> 5, c = idx & 31;
    xs[r][64 + c] = v.x; xs[r][64 + c + 1] = v.y; xs[r][64 + c + 2] = v.z; xs[r][64 + c + 3] = v.w;
  }
  if (tid < DQ) {
    float s = 0.f;
    const float* wrow = &W_ad_k[tid * DQ];
    for (int q = 0; q < DQ; ++q) s += wrow[q] * wa[q];
    u[tid] = s;
  }
  __syncthreads();
  const int r = tid >> 5;
  const int c32 = tid & 31;
  const int d4 = c32 * 4;
  {
    float a0 = b_enc[d4], a1 = b_enc[d4 + 1], a2 = b_enc[d4 + 2], a3 = b_enc[d4 + 3];
    for (int c = 0; c < 96; ++c) {
      const float hv = xs[r][c];
      const float4 w = *(const float4*)&W_enc[c * DQ + d4];
      a0 += hv * w.x; a1 += hv * w.y; a2 += hv * w.z; a3 += hv * w.w;
    }
    hs[r][d4] = a0; hs[r][d4 + 1] = a1; hs[r][d4 + 2] = a2; hs[r][d4 + 3] = a3;
  }
  __syncthreads();
  float part = 0.f;
  for (int c = c32; c < DQ; c += 32) part += hs[r][c] * u[c];
#pragma unroll
  for (int m = 16; m > 0; m >>= 1) part += __shfl_xor(part, m, 32);
  if (c32 == 0) pb[r] = __expf(part);
  __syncthreads();
  v_phase(hs[r], pb[r], W_av_k, b_av_k, r, d4, shh, shl);
  __syncthreads();
  v_store(tid, blk, shh, shl, Vhi, Vlo);
}

// ---- rounds 1,2: P-reduce -> h + sa + p + V' fused (8 rows per block) ----
__global__ __launch_bounds__(256) void kVSR(const float* __restrict__ P,
    const float* __restrict__ W_ad_k, const float* __restrict__ wa,
    const float* __restrict__ W_av_k, const float* __restrict__ b_av_k,
    unsigned short* __restrict__ Vhi, unsigned short* __restrict__ Vlo,
    int ksplit) {
  __shared__ float hs[8][DQ];
  __shared__ float u[DQ];
  __shared__ float pb[8];
  __shared__ __align__(16) unsigned short shh[NT * 128];
  __shared__ __align__(16) unsigned short shl[NT * 128];
  const int tid = threadIdx.x;
  const int r = tid >> 5;
  const int c32 = tid & 31;
  const int d4 = c32 * 4;
  const int j = blockIdx.x * 8 + r;
  if (tid < DQ) {
    float s = 0.f;
    const float* wrow = &W_ad_k[tid * DQ];
    for (int q = 0; q < DQ; ++q) s += wrow[q] * wa[q];
    u[tid] = s;
  }
  float4 num = {0.f, 0.f, 0.f, 0.f};
  float den = 0.f;
  for (int s = 0; s < ksplit; ++s) {
    const float* b = &P[((size_t)s * N + j) * PSTRIDE];
    const float4 v = *(const float4*)&b[d4];
    num.x += v.x; num.y += v.y; num.z += v.z; num.w += v.w;
    den += b[128];
  }
  const float inv = 1.f / den;
  hs[r][d4] = num.x * inv; hs[r][d4 + 1] = num.y * inv;
  hs[r][d4 + 2] = num.z * inv; hs[r][d4 + 3] = num.w * inv;
  __syncthreads();
  float part = 0.f;
  for (int c = c32; c < DQ; c += 32) part += hs[r][c] * u[c];
#pragma unroll
  for (int m = 16; m > 0; m >>= 1) part += __shfl_xor(part, m, 32);
  if (c32 == 0) pb[r] = __expf(part);
  __syncthreads();
  v_phase(hs[r], pb[r], W_av_k, b_av_k, r, d4, shh, shl);
  __syncthreads();
  v_store(tid, blockIdx.x, shh, shl, Vhi, Vlo);
}

// ---- MFMA GEMM: P[s][i][d] = sum_j E[j][i] * V'[j,d] -----------------------
// f16: E single (11-bit mantissa, range [1.01,2.72]), V' = hi+lo split-2.
// One wave per block, 2 i-tiles per wave. PRE rounds: A+B register
// double-buffered across k-steps (loads for t+1 in flight during t's MFMAs).
// Round 0 (!PRE): A from strided trans + exp + f16 cvt, store Ef; B single-buf.
template <bool PRE>
__global__ __launch_bounds__(64, PRE ? 2 : 1) void kGemmM(
    const float* __restrict__ trans, unsigned short* __restrict__ Ef,
    const unsigned short* __restrict__ Vhi, const unsigned short* __restrict__ Vlo,
    float* __restrict__ P, int kchunk) {
  const int lane = threadIdx.x;
  const int quad = lane >> 4, l15 = lane & 15;
  const int it0 = blockIdx.x * 2;                // two adjacent i-tiles
  const int i0 = it0 * 16;
  const int k0 = blockIdx.y * kchunk;
  const int nsteps = kchunk >> 5;
  const size_t kt0 = (size_t)(k0 >> 5);

  f32x4 acc[2][NT];
#pragma unroll
  for (int ti = 0; ti < 2; ++ti)
#pragma unroll
    for (int nt = 0; nt < NT; ++nt) acc[ti][nt] = (f32x4){0.f, 0.f, 0.f, 0.f};

  half8 Bh[NT], Bl[NT], Ah[2];
  float araw[2][8];

  if (PRE) {
#pragma unroll
    for (int nt = 0; nt < NT; ++nt) {
      const size_t bix = ((kt0 * NT + nt) * 64 + lane) * 8;
      Bh[nt] = __builtin_bit_cast(half8, *(const short8*)(Vhi + bix));
      Bl[nt] = __builtin_bit_cast(half8, *(const short8*)(Vlo + bix));
    }
#pragma unroll
    for (int ti = 0; ti < 2; ++ti) {
      const size_t aix = ((kt0 * NIT + it0 + ti) * 64 + lane) * 8;
      Ah[ti] = __builtin_bit_cast(half8, *(const short8*)(Ef + aix));
    }
  } else {
#pragma unroll
    for (int ti = 0; ti < 2; ++ti) {
      const float* aptr = trans + (size_t)(k0 + quad * 8) * N + i0 + ti * 16 + l15;
#pragma unroll
      for (int jj = 0; jj < 8; ++jj) araw[ti][jj] = aptr[(size_t)jj * N];
    }
  }

  for (int t = 0; t < nsteps; ++t) {
    const size_t kt = kt0 + t;
    const bool more = (t + 1 < nsteps);
    half8 nBh[NT], nBl[NT], nAh[2];
    float nar[2][8];
    if (PRE) {
      if (more) {
#pragma unroll
        for (int ti = 0; ti < 2; ++ti) {
          const size_t aix = (((kt + 1) * NIT + it0 + ti) * 64 + lane) * 8;
          nAh[ti] = __builtin_bit_cast(half8, *(const short8*)(Ef + aix));
        }
#pragma unroll
        for (int nt = 0; nt < NT; ++nt) {
          const size_t bix = (((kt + 1) * NT + nt) * 64 + lane) * 8;
          nBh[nt] = __builtin_bit_cast(half8, *(const short8*)(Vhi + bix));
          nBl[nt] = __builtin_bit_cast(half8, *(const short8*)(Vlo + bix));
        }
      }
    } else {
      // single-buffered B: load this step's fragments
#pragma unroll
      for (int nt = 0; nt < NT; ++nt) {
        const size_t bix = ((kt * NT + nt) * 64 + lane) * 8;
        Bh[nt] = __builtin_bit_cast(half8, *(const short8*)(Vhi + bix));
        Bl[nt] = __builtin_bit_cast(half8, *(const short8*)(Vlo + bix));
      }
      if (more) {
#pragma unroll
        for (int ti = 0; ti < 2; ++ti) {
          const float* ap2 = trans + (size_t)(k0 + (t + 1) * 32 + quad * 8) * N + i0 + ti * 16 + l15;
#pragma unroll
          for (int jj = 0; jj < 8; ++jj) nar[ti][jj] = ap2[(size_t)jj * N];
        }
      }
      // exp + f16 convert (each trans element exp'd exactly once), store Ef
#pragma unroll
      for (int ti = 0; ti < 2; ++ti) {
        unsigned short hb[8];
#pragma unroll
        for (int jj = 0; jj < 8; ++jj) hb[jj] = f2h(__expf(araw[ti][jj]));
        const short8 s = {(short)hb[0], (short)hb[1], (short)hb[2], (short)hb[3],
                          (short)hb[4], (short)hb[5], (short)hb[6], (short)hb[7]};
        Ah[ti] = __builtin_bit_cast(half8, s);
        *(short8*)(Ef + ((kt * NIT + it0 + ti) * 64 + lane) * 8) = s;
      }
    }
#pragma unroll
    for (int nt = 0; nt < NT; ++nt) {
#pragma unroll
      for (int ti = 0; ti < 2; ++ti) {
        acc[ti][nt] = __builtin_amdgcn_mfma_f32_16x16x32_f16(Ah[ti], Bh[nt], acc[ti][nt], 0, 0, 0);
        acc[ti][nt] = __builtin_amdgcn_mfma_f32_16x16x32_f16(Ah[ti], Bl[nt], acc[ti][nt], 0, 0, 0);
      }
    }
    if (more) {
      if (PRE) {
        Ah[0] = nAh[0]; Ah[1] = nAh[1];
#pragma unroll
        for (int nt = 0; nt < NT; ++nt) { Bh[nt] = nBh[nt]; Bl[nt] = nBl[nt]; }
      } else {
#pragma unroll
        for (int ti = 0; ti < 2; ++ti)
#pragma unroll
          for (int jj = 0; jj < 8; ++jj) araw[ti][jj] = nar[ti][jj];
      }
    }
  }
  // C layout: col = lane&15, row = quad*4 + reg
  float* Pb = P + (size_t)blockIdx.y * N * PSTRIDE;
#pragma unroll
  for (int ti = 0; ti < 2; ++ti) {
#pragma unroll
    for (int nt = 0; nt < NT; ++nt) {
#pragma unroll
      for (int r = 0; r < 4; ++r) {
        const int i = i0 + ti * 16 + quad * 4 + r;
        Pb[(size_t)i * PSTRIDE + nt * 16 + l15] = acc[ti][nt][r];
      }
    }
  }
}

// ---- final: out[i] = (sum_d num[i][d] W_dec[d]) / den + b_dec ----
__global__ __launch_bounds__(256) void kOutR(const float* __restrict__ P,
    const float* __restrict__ W_dec, const float* __restrict__ b_dec,
    const int* __restrict__ mask, float* __restrict__ out, int ksplit) {
  __shared__ float red[256];
  const int tid = threadIdx.x;
  const int d = tid & 127;
  const int i = blockIdx.x * 2 + (tid >> 7);
  float num = 0.f, den = 0.f;
  for (int s = 0; s < ksplit; ++s) {
    const float* b = &P[((size_t)s * N + i) * PSTRIDE];
    num += b[d];
    den += b[128];
  }
  red[tid] = num * W_dec[d];
  __syncthreads();
  for (int st = 64; st > 0; st >>= 1) {
    if (d < st) red[tid] += red[tid + st];
    __syncthreads();
  }
  if (d == 0) out[i] = (mask[i] == 0) ? -INFINITY : red[tid] / den + b_dec[0];
}

extern "C" void kernel_launch(void* const* d_in, const int* in_sizes, int n_in,
                              void* d_out, int out_size, void* d_ws, size_t ws_size,
                              hipStream_t stream) {
  (void)in_sizes; (void)n_in; (void)out_size;
  const float* x     = (const float*)d_in[0];
  const float* comms = (const float*)d_in[1];
  const float* trans = (const float*)d_in[2];
  const int*   mask  = (const int*)d_in[3];
  const float* W_enc = (const float*)d_in[4];
  const float* b_enc = (const float*)d_in[5];
  const float* W_ad  = (const float*)d_in[6];
  // d_in[7]=b_ad, d_in[9]=b_att cancel inside the row softmax
  const float* w_att = (const float*)d_in[8];
  const float* W_av  = (const float*)d_in[10];
  const float* b_av  = (const float*)d_in[11];
  const float* W_dec = (const float*)d_in[12];
  const float* b_dec = (const float*)d_in[13];
  float* out         = (float*)d_out;

  char* ws = (char*)d_ws;
  unsigned short* Vhi = (unsigned short*)ws;  ws += (size_t)N * PSTRIDE * 2;
  unsigned short* Vlo = (unsigned short*)ws;  ws += (size_t)N * PSTRIDE * 2;
  unsigned short* Ef  = (unsigned short*)ws;  ws += (size_t)N * N * 2;
  float* P = (float*)ws;
  const size_t fixedB = (size_t)N * PSTRIDE * 4 + (size_t)N * N * 2;
  const size_t perB   = (size_t)N * PSTRIDE * 4;          // one P split (fp32)
  const int ksplit = (ws_size >= fixedB + 16 * perB) ? 16 : 8;
  const int kchunk = N / ksplit;

  for (int k = 0; k < 3; ++k) {
    const float* W_ad_k = W_ad + (size_t)k * DQ * DQ;
    const float* wa     = w_att + (size_t)k * 2 * DQ;
    const float* W_av_k = W_av + (size_t)k * DQ * DQ;
    const float* b_av_k = b_av + (size_t)k * DQ;
    if (k == 0) {
      kVS0<<<N / 8, 256, 0, stream>>>(x, comms, W_enc, b_enc, W_ad_k, wa,
                                      W_av_k, b_av_k, Vhi, Vlo);
      kGemmM<false><<<dim3(N / 32, ksplit), 64, 0, stream>>>(
          trans, Ef, Vhi, Vlo, P, kchunk);
    } else {
      kVSR<<<N / 8, 256, 0, stream>>>(P, W_ad_k, wa, W_av_k, b_av_k,
                                      Vhi, Vlo, ksplit);
      kGemmM<true><<<dim3(N / 32, ksplit), 64, 0, stream>>>(
          trans, Ef, Vhi, Vlo, P, kchunk);
    }
  }
  kOutR<<<N / 2, 256, 0, stream>>>(P, W_dec, b_dec, mask, out, ksplit);
}

// Round 8
// 245.922 us; speedup vs baseline: 1.2582x; 1.0485x over previous
//
#include <hip/hip_runtime.h>
#include <math.h>

#define N 4096
#define DQ 128
#define DIN 64
#define DC 32
#define NT 9          // 9 n-tiles of 16: cols 0..127 = v, col 128 = p (z), 129..143 = 0
#define PSTRIDE 144
#define NIT 256       // N/16 i-tiles
#define LDSF (NT * 512)  // shorts per hi (or lo) step-panel: 4608

typedef __attribute__((ext_vector_type(8))) short short8;
typedef __attribute__((ext_vector_type(8))) _Float16 half8;
typedef __attribute__((ext_vector_type(4))) float f32x4;

__device__ __forceinline__ unsigned short f2h(float x) {
  return __builtin_bit_cast(unsigned short, (_Float16)x);
}
__device__ __forceinline__ void async16(unsigned short* lds, const unsigned short* g) {
  __builtin_amdgcn_global_load_lds(
      (const __attribute__((address_space(1))) void*)g,
      (__attribute__((address_space(3))) void*)lds, 16, 0, 0);
}

// ---- kExp: Ef = f16(exp(trans)) in MFMA A-frag layout (the one transpose) ----
// block: 32 j-rows x 64 i-cols; LDS pad 65 -> 2 lanes/bank on both phases.
__global__ __launch_bounds__(256) void kExp(const float* __restrict__ trans,
                                            unsigned short* __restrict__ Ef) {
  __shared__ float sh[32 * 65];
  const int tid = threadIdx.x;
  const int ig = blockIdx.x;        // i-group of 64 (0..63)
  const int kt = blockIdx.y;        // k-tile of 32 (0..127)
  const int r = tid >> 3;           // j within tile
  const int c8 = (tid & 7) * 8;     // i within group
  const float* src = &trans[((size_t)kt * 32 + r) * N + ig * 64 + c8];
  const float4 v0 = *(const float4*)src;
  const float4 v1 = *(const float4*)(src + 4);
  float* d = &sh[r * 65 + c8];
  d[0] = __expf(v0.x); d[1] = __expf(v0.y); d[2] = __expf(v0.z); d[3] = __expf(v0.w);
  d[4] = __expf(v1.x); d[5] = __expf(v1.y); d[6] = __expf(v1.z); d[7] = __expf(v1.w);
  __syncthreads();
  const int itl = tid >> 6;         // 0..3 (i-tile within group)
  const int lane = tid & 63;
  const int quad = lane >> 4, l15 = lane & 15;
  const int col = itl * 16 + l15;
  unsigned short hb[8];
#pragma unroll
  for (int jj = 0; jj < 8; ++jj) hb[jj] = f2h(sh[(quad * 8 + jj) * 65 + col]);
  const short8 s = {(short)hb[0], (short)hb[1], (short)hb[2], (short)hb[3],
                    (short)hb[4], (short)hb[5], (short)hb[6], (short)hb[7]};
  *(short8*)(Ef + (((size_t)kt * NIT + ig * 4 + itl) * 64 + lane) * 8) = s;
}

// ---- shared epilogue: p*(h@W_av+b_av) -> f16 hi/lo into LDS tile -----------
__device__ __forceinline__ void v_phase(const float* hs_row, float p,
    const float* __restrict__ W_av_k, const float* __restrict__ b_av_k,
    int r, int d4, unsigned short* shh, unsigned short* shl) {
  float a[4] = {b_av_k[d4], b_av_k[d4 + 1], b_av_k[d4 + 2], b_av_k[d4 + 3]};
  for (int c = 0; c < DQ; ++c) {
    const float hv = hs_row[c];
    const float4 w = *(const float4*)&W_av_k[c * DQ + d4];
    a[0] += hv * w.x; a[1] += hv * w.y; a[2] += hv * w.z; a[3] += hv * w.w;
  }
  const int nt = d4 >> 4;
#pragma unroll
  for (int e = 0; e < 4; ++e) {
    const float val = p * a[e];
    const _Float16 hi = (_Float16)val;
    const _Float16 lo = (_Float16)(val - (float)hi);
    const int ix = nt * 128 + ((d4 + e) & 15) * 8 + r;
    shh[ix] = __builtin_bit_cast(unsigned short, hi);
    shl[ix] = __builtin_bit_cast(unsigned short, lo);
  }
  const int c32 = d4 >> 2;
  if (c32 < 16) {
    const int ix = 8 * 128 + c32 * 8 + r;
    if (c32 == 0) {
      const _Float16 phi = (_Float16)p;
      const _Float16 plo = (_Float16)(p - (float)phi);
      shh[ix] = __builtin_bit_cast(unsigned short, phi);
      shl[ix] = __builtin_bit_cast(unsigned short, plo);
    } else {
      shh[ix] = 0; shl[ix] = 0;
    }
  }
}

__device__ __forceinline__ void v_store(int tid, int blk,
    const unsigned short* shh, const unsigned short* shl,
    unsigned short* __restrict__ Vhi, unsigned short* __restrict__ Vlo) {
  const int kt = blk >> 2, quad = blk & 3;
  if (tid < NT * 16) {
    const int nt = tid >> 4, l15 = tid & 15;
    const size_t dst = (((size_t)kt * NT + nt) * 64 + quad * 16 + l15) * 8;
    *(short8*)(Vhi + dst) = *(const short8*)&shh[nt * 128 + l15 * 8];
    *(short8*)(Vlo + dst) = *(const short8*)&shl[nt * 128 + l15 * 8];
  }
}

// ---- round 0: encode + sa + p + V' fused (8 rows per block) ----
__global__ __launch_bounds__(256) void kVS0(const float* __restrict__ x,
    const float* __restrict__ comms, const float* __restrict__ W_enc,
    const float* __restrict__ b_enc, const float* __restrict__ W_ad_k,
    const float* __restrict__ wa, const float* __restrict__ W_av_k,
    const float* __restrict__ b_av_k,
    unsigned short* __restrict__ Vhi, unsigned short* __restrict__ Vlo) {
  __shared__ float xs[8][96];
  __shared__ float hs[8][DQ];
  __shared__ float u[DQ];
  __shared__ float pb[8];
  __shared__ __align__(16) unsigned short shh[NT * 128];
  __shared__ __align__(16) unsigned short shl[NT * 128];
  const int tid = threadIdx.x;
  const int blk = blockIdx.x;
  if (tid < 128) {
    const float4 v = *(const float4*)&x[(size_t)blk * 8 * DIN + tid * 4];
    const int idx = tid * 4, r = idx >> 6, c = idx & 63;
    xs[r][c] = v.x; xs[r][c + 1] = v.y; xs[r][c + 2] = v.z; xs[r][c + 3] = v.w;
  } else if (tid < 192) {
    const int t = tid - 128;
    const float4 v = *(const float4*)&comms[(size_t)blk * 8 * DC + t * 4];
    const int idx = t * 4, r = idx >> 5, c = idx & 31;
    xs[r][64 + c] = v.x; xs[r][64 + c + 1] = v.y; xs[r][64 + c + 2] = v.z; xs[r][64 + c + 3] = v.w;
  }
  if (tid < DQ) {
    float s = 0.f;
    const float* wrow = &W_ad_k[tid * DQ];
    for (int q = 0; q < DQ; ++q) s += wrow[q] * wa[q];
    u[tid] = s;
  }
  __syncthreads();
  const int r = tid >> 5;
  const int c32 = tid & 31;
  const int d4 = c32 * 4;
  {
    float a0 = b_enc[d4], a1 = b_enc[d4 + 1], a2 = b_enc[d4 + 2], a3 = b_enc[d4 + 3];
    for (int c = 0; c < 96; ++c) {
      const float hv = xs[r][c];
      const float4 w = *(const float4*)&W_enc[c * DQ + d4];
      a0 += hv * w.x; a1 += hv * w.y; a2 += hv * w.z; a3 += hv * w.w;
    }
    hs[r][d4] = a0; hs[r][d4 + 1] = a1; hs[r][d4 + 2] = a2; hs[r][d4 + 3] = a3;
  }
  __syncthreads();
  float part = 0.f;
  for (int c = c32; c < DQ; c += 32) part += hs[r][c] * u[c];
#pragma unroll
  for (int m = 16; m > 0; m >>= 1) part += __shfl_xor(part, m, 32);
  if (c32 == 0) pb[r] = __expf(part);
  __syncthreads();
  v_phase(hs[r], pb[r], W_av_k, b_av_k, r, d4, shh, shl);
  __syncthreads();
  v_store(tid, blk, shh, shl, Vhi, Vlo);
}

// ---- rounds 1,2: P-reduce -> h + sa + p + V' fused (8 rows per block) ----
__global__ __launch_bounds__(256) void kVSR(const float* __restrict__ P,
    const float* __restrict__ W_ad_k, const float* __restrict__ wa,
    const float* __restrict__ W_av_k, const float* __restrict__ b_av_k,
    unsigned short* __restrict__ Vhi, unsigned short* __restrict__ Vlo,
    int ksplit) {
  __shared__ float hs[8][DQ];
  __shared__ float u[DQ];
  __shared__ float pb[8];
  __shared__ __align__(16) unsigned short shh[NT * 128];
  __shared__ __align__(16) unsigned short shl[NT * 128];
  const int tid = threadIdx.x;
  const int r = tid >> 5;
  const int c32 = tid & 31;
  const int d4 = c32 * 4;
  const int j = blockIdx.x * 8 + r;
  if (tid < DQ) {
    float s = 0.f;
    const float* wrow = &W_ad_k[tid * DQ];
    for (int q = 0; q < DQ; ++q) s += wrow[q] * wa[q];
    u[tid] = s;
  }
  float4 num = {0.f, 0.f, 0.f, 0.f};
  float den = 0.f;
  for (int s = 0; s < ksplit; ++s) {
    const float* b = &P[((size_t)s * N + j) * PSTRIDE];
    const float4 v = *(const float4*)&b[d4];
    num.x += v.x; num.y += v.y; num.z += v.z; num.w += v.w;
    den += b[128];
  }
  const float inv = 1.f / den;
  hs[r][d4] = num.x * inv; hs[r][d4 + 1] = num.y * inv;
  hs[r][d4 + 2] = num.z * inv; hs[r][d4 + 3] = num.w * inv;
  __syncthreads();
  float part = 0.f;
  for (int c = c32; c < DQ; c += 32) part += hs[r][c] * u[c];
#pragma unroll
  for (int m = 16; m > 0; m >>= 1) part += __shfl_xor(part, m, 32);
  if (c32 == 0) pb[r] = __expf(part);
  __syncthreads();
  v_phase(hs[r], pb[r], W_av_k, b_av_k, r, d4, shh, shl);
  __syncthreads();
  v_store(tid, blockIdx.x, shh, shl, Vhi, Vlo);
}

// ---- MFMA GEMM: P[s][i][d] = sum_j E[j][i]*V'[j][d]; B via LDS dbuf ---------
// 4 waves x 2 i-tiles = 128 rows/block. Per k-step: stage t+1 B-panel (18KB)
// via global_load_lds, prefetch t+1 A-frags, ds_read+MFMA on t, one barrier.
__global__ __launch_bounds__(256) void kGemm(
    const unsigned short* __restrict__ Ef,
    const unsigned short* __restrict__ Vhi, const unsigned short* __restrict__ Vlo,
    float* __restrict__ P, int nsteps) {
  __shared__ __align__(16) unsigned short ldsB[2][2 * LDSF];  // 2 x 18KB
  const int tid = threadIdx.x;
  const int w = tid >> 6, lane = tid & 63;
  const int quad = lane >> 4, l15 = lane & 15;
  const int it0 = blockIdx.x * 8 + w * 2;
  const size_t kt0 = (size_t)blockIdx.y * nsteps;

  // stage step 0 B-panel: 18 chunks of 1KB, wave w takes chunks w, w+4, ...
#pragma unroll
  for (int c = w; c < 2 * NT; c += 4) {
    const unsigned short* g = (c < NT)
        ? Vhi + (kt0 * NT + c) * 512 + lane * 8
        : Vlo + (kt0 * NT + (c - NT)) * 512 + lane * 8;
    async16(&ldsB[0][c * 512], g);
  }
  half8 Ah[2];
#pragma unroll
  for (int ti = 0; ti < 2; ++ti)
    Ah[ti] = __builtin_bit_cast(half8,
        *(const short8*)(Ef + ((kt0 * NIT + it0 + ti) * 64 + lane) * 8));
  f32x4 acc[2][NT];
#pragma unroll
  for (int ti = 0; ti < 2; ++ti)
#pragma unroll
    for (int nt = 0; nt < NT; ++nt) acc[ti][nt] = (f32x4){0.f, 0.f, 0.f, 0.f};
  __syncthreads();  // drains vmcnt: buf0 + A(0) ready

  for (int t = 0; t < nsteps; ++t) {
    const bool more = (t + 1 < nsteps);
    half8 nAh[2];
    if (more) {
      const size_t ktn = kt0 + t + 1;
#pragma unroll
      for (int c = w; c < 2 * NT; c += 4) {
        const unsigned short* g = (c < NT)
            ? Vhi + (ktn * NT + c) * 512 + lane * 8
            : Vlo + (ktn * NT + (c - NT)) * 512 + lane * 8;
        async16(&ldsB[(t + 1) & 1][c * 512], g);
      }
#pragma unroll
      for (int ti = 0; ti < 2; ++ti)
        nAh[ti] = __builtin_bit_cast(half8,
            *(const short8*)(Ef + ((ktn * NIT + it0 + ti) * 64 + lane) * 8));
    }
    const unsigned short* bb = ldsB[t & 1];
#pragma unroll
    for (int nt = 0; nt < NT; ++nt) {
      const half8 Bh = __builtin_bit_cast(half8, *(const short8*)(bb + nt * 512 + lane * 8));
      const half8 Bl = __builtin_bit_cast(half8, *(const short8*)(bb + LDSF + nt * 512 + lane * 8));
      acc[0][nt] = __builtin_amdgcn_mfma_f32_16x16x32_f16(Ah[0], Bh, acc[0][nt], 0, 0, 0);
      acc[0][nt] = __builtin_amdgcn_mfma_f32_16x16x32_f16(Ah[0], Bl, acc[0][nt], 0, 0, 0);
      acc[1][nt] = __builtin_amdgcn_mfma_f32_16x16x32_f16(Ah[1], Bh, acc[1][nt], 0, 0, 0);
      acc[1][nt] = __builtin_amdgcn_mfma_f32_16x16x32_f16(Ah[1], Bl, acc[1][nt], 0, 0, 0);
    }
    if (more) {
      Ah[0] = nAh[0]; Ah[1] = nAh[1];
      __syncthreads();  // staging t+1 drained; buf t fully consumed
    }
  }
  // C layout: col = lane&15, row = quad*4 + reg
  float* Pb = P + (size_t)blockIdx.y * N * PSTRIDE;
#pragma unroll
  for (int ti = 0; ti < 2; ++ti) {
#pragma unroll
    for (int nt = 0; nt < NT; ++nt) {
#pragma unroll
      for (int r = 0; r < 4; ++r) {
        const int i = (it0 + ti) * 16 + quad * 4 + r;
        Pb[(size_t)i * PSTRIDE + nt * 16 + l15] = acc[ti][nt][r];
      }
    }
  }
}

// ---- final: out[i] = (sum_d num[i][d] W_dec[d]) / den + b_dec ----
__global__ __launch_bounds__(256) void kOutR(const float* __restrict__ P,
    const float* __restrict__ W_dec, const float* __restrict__ b_dec,
    const int* __restrict__ mask, float* __restrict__ out, int ksplit) {
  __shared__ float red[256];
  const int tid = threadIdx.x;
  const int d = tid & 127;
  const int i = blockIdx.x * 2 + (tid >> 7);
  float num = 0.f, den = 0.f;
  for (int s = 0; s < ksplit; ++s) {
    const float* b = &P[((size_t)s * N + i) * PSTRIDE];
    num += b[d];
    den += b[128];
  }
  red[tid] = num * W_dec[d];
  __syncthreads();
  for (int st = 64; st > 0; st >>= 1) {
    if (d < st) red[tid] += red[tid + st];
    __syncthreads();
  }
  if (d == 0) out[i] = (mask[i] == 0) ? -INFINITY : red[tid] / den + b_dec[0];
}

extern "C" void kernel_launch(void* const* d_in, const int* in_sizes, int n_in,
                              void* d_out, int out_size, void* d_ws, size_t ws_size,
                              hipStream_t stream) {
  (void)in_sizes; (void)n_in; (void)out_size;
  const float* x     = (const float*)d_in[0];
  const float* comms = (const float*)d_in[1];
  const float* trans = (const float*)d_in[2];
  const int*   mask  = (const int*)d_in[3];
  const float* W_enc = (const float*)d_in[4];
  const float* b_enc = (const float*)d_in[5];
  const float* W_ad  = (const float*)d_in[6];
  // d_in[7]=b_ad, d_in[9]=b_att cancel inside the row softmax
  const float* w_att = (const float*)d_in[8];
  const float* W_av  = (const float*)d_in[10];
  const float* b_av  = (const float*)d_in[11];
  const float* W_dec = (const float*)d_in[12];
  const float* b_dec = (const float*)d_in[13];
  float* out         = (float*)d_out;

  char* ws = (char*)d_ws;
  unsigned short* Vhi = (unsigned short*)ws;  ws += (size_t)N * PSTRIDE * 2;
  unsigned short* Vlo = (unsigned short*)ws;  ws += (size_t)N * PSTRIDE * 2;
  unsigned short* Ef  = (unsigned short*)ws;  ws += (size_t)N * N * 2;
  float* P = (float*)ws;
  const size_t fixedB = (size_t)N * PSTRIDE * 4 + (size_t)N * N * 2;
  const size_t perB   = (size_t)N * PSTRIDE * 4;          // one P split (fp32)
  const int ksplit = (ws_size >= fixedB + 16 * perB) ? 16 : 8;
  const int nsteps = (N / ksplit) >> 5;

  kExp<<<dim3(64, 128), 256, 0, stream>>>(trans, Ef);
  for (int k = 0; k < 3; ++k) {
    const float* W_ad_k = W_ad + (size_t)k * DQ * DQ;
    const float* wa     = w_att + (size_t)k * 2 * DQ;
    const float* W_av_k = W_av + (size_t)k * DQ * DQ;
    const float* b_av_k = b_av + (size_t)k * DQ;
    if (k == 0) {
      kVS0<<<N / 8, 256, 0, stream>>>(x, comms, W_enc, b_enc, W_ad_k, wa,
                                      W_av_k, b_av_k, Vhi, Vlo);
    } else {
      kVSR<<<N / 8, 256, 0, stream>>>(P, W_ad_k, wa, W_av_k, b_av_k,
                                      Vhi, Vlo, ksplit);
    }
    kGemm<<<dim3(NIT / 8, ksplit), 256, 0, stream>>>(Ef, Vhi, Vlo, P, nsteps);
  }
  kOutR<<<N / 2, 256, 0, stream>>>(P, W_dec, b_dec, mask, out, ksplit);
}

// Round 9
// 227.511 us; speedup vs baseline: 1.3600x; 1.0809x over previous
//
#include <hip/hip_runtime.h>
#include <math.h>

#define N 4096
#define DQ 128
#define DIN 64
#define DC 32
#define NT 9          // full B panel: 9 n-tiles (128 v cols + z tile)
#define PST9 144
#define PST1 16
#define NIT 256       // N/16 i-tiles

typedef __attribute__((ext_vector_type(8))) short short8;
typedef __attribute__((ext_vector_type(8))) _Float16 half8;
typedef __attribute__((ext_vector_type(4))) float f32x4;

__device__ __forceinline__ unsigned short f2h(float x) {
  return __builtin_bit_cast(unsigned short, (_Float16)x);
}
__device__ __forceinline__ void async16(unsigned short* lds, const unsigned short* g) {
  __builtin_amdgcn_global_load_lds(
      (const __attribute__((address_space(1))) void*)g,
      (__attribute__((address_space(3))) void*)lds, 16, 0, 0);
}

// ---- kExp: Ef = f16(exp(trans)) in MFMA A-frag layout (the one transpose) ----
__global__ __launch_bounds__(256) void kExp(const float* __restrict__ trans,
                                            unsigned short* __restrict__ Ef) {
  __shared__ float sh[32 * 65];
  const int tid = threadIdx.x;
  const int ig = blockIdx.x;        // i-group of 64
  const int kt = blockIdx.y;        // k-tile of 32
  const int r = tid >> 3;
  const int c8 = (tid & 7) * 8;
  const float* src = &trans[((size_t)kt * 32 + r) * N + ig * 64 + c8];
  const float4 v0 = *(const float4*)src;
  const float4 v1 = *(const float4*)(src + 4);
  float* d = &sh[r * 65 + c8];
  d[0] = __expf(v0.x); d[1] = __expf(v0.y); d[2] = __expf(v0.z); d[3] = __expf(v0.w);
  d[4] = __expf(v1.x); d[5] = __expf(v1.y); d[6] = __expf(v1.z); d[7] = __expf(v1.w);
  __syncthreads();
  const int itl = tid >> 6;
  const int lane = tid & 63;
  const int quad = lane >> 4, l15 = lane & 15;
  const int col = itl * 16 + l15;
  unsigned short hb[8];
#pragma unroll
  for (int jj = 0; jj < 8; ++jj) hb[jj] = f2h(sh[(quad * 8 + jj) * 65 + col]);
  const short8 s = {(short)hb[0], (short)hb[1], (short)hb[2], (short)hb[3],
                    (short)hb[4], (short)hb[5], (short)hb[6], (short)hb[7]};
  *(short8*)(Ef + (((size_t)kt * NIT + ig * 4 + itl) * 64 + lane) * 8) = s;
}

// ---- shared epilogue: p*(h@W_av+b_av) -> single f16 into LDS tile -----------
__device__ __forceinline__ void v_phase(const float* hs_row, float p,
    const float* __restrict__ W_av_k, const float* __restrict__ b_av_k,
    int r, int d4, unsigned short* shh) {
  float a[4] = {b_av_k[d4], b_av_k[d4 + 1], b_av_k[d4 + 2], b_av_k[d4 + 3]};
  for (int c = 0; c < DQ; ++c) {
    const float hv = hs_row[c];
    const float4 w = *(const float4*)&W_av_k[c * DQ + d4];
    a[0] += hv * w.x; a[1] += hv * w.y; a[2] += hv * w.z; a[3] += hv * w.w;
  }
  const int nt = d4 >> 4;
#pragma unroll
  for (int e = 0; e < 4; ++e)
    shh[nt * 128 + ((d4 + e) & 15) * 8 + r] = f2h(p * a[e]);
  const int c32 = d4 >> 2;
  if (c32 < 16)
    shh[8 * 128 + c32 * 8 + r] = (c32 == 0) ? f2h(p) : 0;
}

__device__ __forceinline__ void v_store(int tid, int blk,
    const unsigned short* shh, unsigned short* __restrict__ Vf) {
  const int kt = blk >> 2, quad = blk & 3;
  if (tid < NT * 16) {
    const int nt = tid >> 4, l15 = tid & 15;
    const size_t dst = (((size_t)kt * NT + nt) * 64 + quad * 16 + l15) * 8;
    *(short8*)(Vf + dst) = *(const short8*)&shh[nt * 128 + l15 * 8];
  }
}

// ---- round 0: encode + sa + p + V' fused (8 rows per block) ----
__global__ __launch_bounds__(256) void kVS0(const float* __restrict__ x,
    const float* __restrict__ comms, const float* __restrict__ W_enc,
    const float* __restrict__ b_enc, const float* __restrict__ W_ad_k,
    const float* __restrict__ wa, const float* __restrict__ W_av_k,
    const float* __restrict__ b_av_k, unsigned short* __restrict__ Vf) {
  __shared__ float xs[8][96];
  __shared__ float hs[8][DQ];
  __shared__ float u[DQ];
  __shared__ float pb[8];
  __shared__ __align__(16) unsigned short shh[NT * 128];
  const int tid = threadIdx.x;
  const int blk = blockIdx.x;
  if (tid < 128) {
    const float4 v = *(const float4*)&x[(size_t)blk * 8 * DIN + tid * 4];
    const int idx = tid * 4, r = idx >> 6, c = idx & 63;
    xs[r][c] = v.x; xs[r][c + 1] = v.y; xs[r][c + 2] = v.z; xs[r][c + 3] = v.w;
  } else if (tid < 192) {
    const int t = tid - 128;
    const float4 v = *(const float4*)&comms[(size_t)blk * 8 * DC + t * 4];
    const int idx = t * 4, r = idx >> 5, c = idx & 31;
    xs[r][64 + c] = v.x; xs[r][64 + c + 1] = v.y; xs[r][64 + c + 2] = v.z; xs[r][64 + c + 3] = v.w;
  }
  if (tid < DQ) {
    float s = 0.f;
    const float* wrow = &W_ad_k[tid * DQ];
    for (int q = 0; q < DQ; ++q) s += wrow[q] * wa[q];
    u[tid] = s;
  }
  __syncthreads();
  const int r = tid >> 5;
  const int c32 = tid & 31;
  const int d4 = c32 * 4;
  {
    float a0 = b_enc[d4], a1 = b_enc[d4 + 1], a2 = b_enc[d4 + 2], a3 = b_enc[d4 + 3];
    for (int c = 0; c < 96; ++c) {
      const float hv = xs[r][c];
      const float4 w = *(const float4*)&W_enc[c * DQ + d4];
      a0 += hv * w.x; a1 += hv * w.y; a2 += hv * w.z; a3 += hv * w.w;
    }
    hs[r][d4] = a0; hs[r][d4 + 1] = a1; hs[r][d4 + 2] = a2; hs[r][d4 + 3] = a3;
  }
  __syncthreads();
  float part = 0.f;
  for (int c = c32; c < DQ; c += 32) part += hs[r][c] * u[c];
#pragma unroll
  for (int m = 16; m > 0; m >>= 1) part += __shfl_xor(part, m, 32);
  if (c32 == 0) pb[r] = __expf(part);
  __syncthreads();
  v_phase(hs[r], pb[r], W_av_k, b_av_k, r, d4, shh);
  __syncthreads();
  v_store(tid, blk, shh, Vf);
}

// ---- round 1: P-reduce -> h + sa + p + V' (full panel) ----
__global__ __launch_bounds__(256) void kVSR(const float* __restrict__ P,
    const float* __restrict__ W_ad_k, const float* __restrict__ wa,
    const float* __restrict__ W_av_k, const float* __restrict__ b_av_k,
    unsigned short* __restrict__ Vf, int ksplit) {
  __shared__ float hs[8][DQ];
  __shared__ float u[DQ];
  __shared__ float pb[8];
  __shared__ __align__(16) unsigned short shh[NT * 128];
  const int tid = threadIdx.x;
  const int r = tid >> 5;
  const int c32 = tid & 31;
  const int d4 = c32 * 4;
  const int j = blockIdx.x * 8 + r;
  if (tid < DQ) {
    float s = 0.f;
    const float* wrow = &W_ad_k[tid * DQ];
    for (int q = 0; q < DQ; ++q) s += wrow[q] * wa[q];
    u[tid] = s;
  }
  float4 num = {0.f, 0.f, 0.f, 0.f};
  float den = 0.f;
  for (int s = 0; s < ksplit; ++s) {
    const float* b = &P[((size_t)s * N + j) * PST9];
    const float4 v = *(const float4*)&b[d4];
    num.x += v.x; num.y += v.y; num.z += v.z; num.w += v.w;
    den += b[128];
  }
  const float inv = 1.f / den;
  hs[r][d4] = num.x * inv; hs[r][d4 + 1] = num.y * inv;
  hs[r][d4 + 2] = num.z * inv; hs[r][d4 + 3] = num.w * inv;
  __syncthreads();
  float part = 0.f;
  for (int c = c32; c < DQ; c += 32) part += hs[r][c] * u[c];
#pragma unroll
  for (int m = 16; m > 0; m >>= 1) part += __shfl_xor(part, m, 32);
  if (c32 == 0) pb[r] = __expf(part);
  __syncthreads();
  v_phase(hs[r], pb[r], W_av_k, b_av_k, r, d4, shh);
  __syncthreads();
  v_store(tid, blockIdx.x, shh, Vf);
}

// ---- round 2: P-reduce -> h + sa + p + CONTRACTED V' (v.W_dec, p) ----
__global__ __launch_bounds__(256) void kVSRc(const float* __restrict__ P,
    const float* __restrict__ W_ad_k, const float* __restrict__ wa,
    const float* __restrict__ W_av_k, const float* __restrict__ b_av_k,
    const float* __restrict__ W_dec, unsigned short* __restrict__ Vc,
    int ksplit) {
  __shared__ float hs[8][DQ];
  __shared__ float u[DQ];
  __shared__ float pb[8];
  const int tid = threadIdx.x;
  const int r = tid >> 5;
  const int c32 = tid & 31;
  const int d4 = c32 * 4;
  const int j = blockIdx.x * 8 + r;
  if (tid < DQ) {
    float s = 0.f;
    const float* wrow = &W_ad_k[tid * DQ];
    for (int q = 0; q < DQ; ++q) s += wrow[q] * wa[q];
    u[tid] = s;
  }
  float4 num = {0.f, 0.f, 0.f, 0.f};
  float den = 0.f;
  for (int s = 0; s < ksplit; ++s) {
    const float* b = &P[((size_t)s * N + j) * PST9];
    const float4 v = *(const float4*)&b[d4];
    num.x += v.x; num.y += v.y; num.z += v.z; num.w += v.w;
    den += b[128];
  }
  const float inv = 1.f / den;
  hs[r][d4] = num.x * inv; hs[r][d4 + 1] = num.y * inv;
  hs[r][d4 + 2] = num.z * inv; hs[r][d4 + 3] = num.w * inv;
  __syncthreads();
  float part = 0.f;
  for (int c = c32; c < DQ; c += 32) part += hs[r][c] * u[c];
#pragma unroll
  for (int m = 16; m > 0; m >>= 1) part += __shfl_xor(part, m, 32);
  if (c32 == 0) pb[r] = __expf(part);
  __syncthreads();
  // v = h@W_av + b_av, contracted against W_dec
  float a[4] = {b_av_k[d4], b_av_k[d4 + 1], b_av_k[d4 + 2], b_av_k[d4 + 3]};
  for (int c = 0; c < DQ; ++c) {
    const float hv = hs[r][c];
    const float4 w = *(const float4*)&W_av_k[c * DQ + d4];
    a[0] += hv * w.x; a[1] += hv * w.y; a[2] += hv * w.z; a[3] += hv * w.w;
  }
  float vd = a[0] * W_dec[d4] + a[1] * W_dec[d4 + 1]
           + a[2] * W_dec[d4 + 2] + a[3] * W_dec[d4 + 3];
#pragma unroll
  for (int m = 16; m > 0; m >>= 1) vd += __shfl_xor(vd, m, 32);  // all-reduce
  const float p = pb[r];
  if (c32 < 16) {
    const int blk = blockIdx.x;
    const size_t ix = (((size_t)(blk >> 2)) * 64 + (blk & 3) * 16 + c32) * 8 + r;
    Vc[ix] = (c32 == 0) ? f2h(p * vd) : (c32 == 1) ? f2h(p) : 0;
  }
}

// ---- MFMA GEMM: P[s][i][d] = sum_j E[j][i]*V'[j][d]; B via LDS dbuf ---------
// 2 waves x 2 i-tiles = 64 rows/block; single-f16 B panel NTT KB/step.
template <int NTT, int PST>
__global__ __launch_bounds__(128) void kGemm(
    const unsigned short* __restrict__ Ef, const unsigned short* __restrict__ Vf,
    float* __restrict__ P, int nsteps) {
  __shared__ __align__(16) unsigned short ldsB[2][NTT * 512];
  const int tid = threadIdx.x;
  const int w = tid >> 6, lane = tid & 63;
  const int quad = lane >> 4, l15 = lane & 15;
  const int it0 = blockIdx.x * 4 + w * 2;
  const size_t kt0 = (size_t)blockIdx.y * nsteps;

  for (int c = w; c < NTT; c += 2)
    async16(&ldsB[0][c * 512], Vf + (kt0 * NTT + c) * 512 + lane * 8);
  half8 Ah[2];
#pragma unroll
  for (int ti = 0; ti < 2; ++ti)
    Ah[ti] = __builtin_bit_cast(half8,
        *(const short8*)(Ef + ((kt0 * NIT + it0 + ti) * 64 + lane) * 8));
  f32x4 acc[2][NTT];
#pragma unroll
  for (int ti = 0; ti < 2; ++ti)
#pragma unroll
    for (int nt = 0; nt < NTT; ++nt) acc[ti][nt] = (f32x4){0.f, 0.f, 0.f, 0.f};
  __syncthreads();

  for (int t = 0; t < nsteps; ++t) {
    const bool more = (t + 1 < nsteps);
    half8 nAh[2];
    if (more) {
      const size_t ktn = kt0 + t + 1;
      for (int c = w; c < NTT; c += 2)
        async16(&ldsB[(t + 1) & 1][c * 512], Vf + (ktn * NTT + c) * 512 + lane * 8);
#pragma unroll
      for (int ti = 0; ti < 2; ++ti)
        nAh[ti] = __builtin_bit_cast(half8,
            *(const short8*)(Ef + ((ktn * NIT + it0 + ti) * 64 + lane) * 8));
    }
    const unsigned short* bb = ldsB[t & 1];
#pragma unroll
    for (int nt = 0; nt < NTT; ++nt) {
      const half8 Bh = __builtin_bit_cast(half8, *(const short8*)(bb + nt * 512 + lane * 8));
      acc[0][nt] = __builtin_amdgcn_mfma_f32_16x16x32_f16(Ah[0], Bh, acc[0][nt], 0, 0, 0);
      acc[1][nt] = __builtin_amdgcn_mfma_f32_16x16x32_f16(Ah[1], Bh, acc[1][nt], 0, 0, 0);
    }
    if (more) {
      Ah[0] = nAh[0]; Ah[1] = nAh[1];
      __syncthreads();
    }
  }
  float* Pb = P + (size_t)blockIdx.y * N * PST;
#pragma unroll
  for (int ti = 0; ti < 2; ++ti) {
#pragma unroll
    for (int nt = 0; nt < NTT; ++nt) {
#pragma unroll
      for (int r = 0; r < 4; ++r) {
        const int i = (it0 + ti) * 16 + quad * 4 + r;
        Pb[(size_t)i * PST + nt * 16 + l15] = acc[ti][nt][r];
      }
    }
  }
}

// ---- final: out[i] = numc/den + b_dec (P3 has 2 live cols) ----
__global__ __launch_bounds__(256) void kOut(const float* __restrict__ P3,
    const float* __restrict__ b_dec, const int* __restrict__ mask,
    float* __restrict__ out, int ksplit) {
  const int i = blockIdx.x * 256 + threadIdx.x;
  float num = 0.f, den = 0.f;
  for (int s = 0; s < ksplit; ++s) {
    const float* b = &P3[((size_t)s * N + i) * PST1];
    num += b[0];
    den += b[1];
  }
  out[i] = (mask[i] == 0) ? -INFINITY : num / den + b_dec[0];
}

extern "C" void kernel_launch(void* const* d_in, const int* in_sizes, int n_in,
                              void* d_out, int out_size, void* d_ws, size_t ws_size,
                              hipStream_t stream) {
  (void)in_sizes; (void)n_in; (void)out_size;
  const float* x     = (const float*)d_in[0];
  const float* comms = (const float*)d_in[1];
  const float* trans = (const float*)d_in[2];
  const int*   mask  = (const int*)d_in[3];
  const float* W_enc = (const float*)d_in[4];
  const float* b_enc = (const float*)d_in[5];
  const float* W_ad  = (const float*)d_in[6];
  // d_in[7]=b_ad, d_in[9]=b_att cancel inside the row softmax
  const float* w_att = (const float*)d_in[8];
  const float* W_av  = (const float*)d_in[10];
  const float* b_av  = (const float*)d_in[11];
  const float* W_dec = (const float*)d_in[12];
  const float* b_dec = (const float*)d_in[13];
  float* out         = (float*)d_out;

  char* ws = (char*)d_ws;
  unsigned short* Vf = (unsigned short*)ws;  ws += (size_t)(N / 32) * NT * 512 * 2;
  unsigned short* Vc = (unsigned short*)ws;  ws += (size_t)(N / 32) * 512 * 2;
  unsigned short* Ef = (unsigned short*)ws;  ws += (size_t)N * N * 2;
  float* P  = (float*)ws;
  const size_t fixedB = (size_t)(N / 32) * (NT + 1) * 1024 + (size_t)N * N * 2;
  const size_t perB   = (size_t)N * (PST9 + PST1) * 4;
  const int ksplit = (ws_size >= fixedB + 16 * perB) ? 16 : 8;
  float* P3 = P + (size_t)ksplit * N * PST9;
  const int nsteps = (N / ksplit) >> 5;

  kExp<<<dim3(64, 128), 256, 0, stream>>>(trans, Ef);
  const float* wa1 = w_att;
  kVS0<<<N / 8, 256, 0, stream>>>(x, comms, W_enc, b_enc, W_ad, wa1,
                                  W_av, b_av, Vf);
  kGemm<NT, PST9><<<dim3(NIT / 4, ksplit), 128, 0, stream>>>(Ef, Vf, P, nsteps);

  kVSR<<<N / 8, 256, 0, stream>>>(P, W_ad + (size_t)1 * DQ * DQ,
                                  w_att + 2 * DQ, W_av + (size_t)1 * DQ * DQ,
                                  b_av + DQ, Vf, ksplit);
  kGemm<NT, PST9><<<dim3(NIT / 4, ksplit), 128, 0, stream>>>(Ef, Vf, P, nsteps);

  kVSRc<<<N / 8, 256, 0, stream>>>(P, W_ad + (size_t)2 * DQ * DQ,
                                   w_att + 4 * DQ, W_av + (size_t)2 * DQ * DQ,
                                   b_av + 2 * DQ, W_dec, Vc, ksplit);
  kGemm<1, PST1><<<dim3(NIT / 4, ksplit), 128, 0, stream>>>(Ef, Vc, P3, nsteps);

  kOut<<<N / 256, 256, 0, stream>>>(P3, b_dec, mask, out, ksplit);
}